// Round 7
// baseline (242.438 us; speedup 1.0000x reference)
//
#include <hip/hip_runtime.h>
#include <hip/hip_bf16.h>

#define DEVINL __device__ __forceinline__

typedef __attribute__((ext_vector_type(8))) short short8;   // 8 bf16 (4 VGPRs)
typedef __attribute__((ext_vector_type(4))) float f32x4;    // MFMA acc

DEVINL float rcp_f(float x) { return __builtin_amdgcn_rcpf(x); }

// compiler-level memory barrier (gram tile handoff only)
#define LDS_FENCE() __asm__ volatile("" ::: "memory")

template<int CTRL>
DEVINL float dpp_mov(float x) {
  return __int_as_float(__builtin_amdgcn_update_dpp(
      0, __float_as_int(x), CTRL, 0xF, 0xF, true));
}
DEVINL float readlane_f(float v, int lane) {   // lane is compile-time const
  return __int_as_float(__builtin_amdgcn_readlane(__float_as_int(v), lane));
}
DEVINL float readfirst_f(float v) {
  return __int_as_float(__builtin_amdgcn_readfirstlane(__float_as_int(v)));
}

// Mirrored row layout: lanes 0-15 = rows 0-15 (copy0), 16-31 = rows 0-15
// (copy1), 32-47 = rows 16-31 (copy0), 48-63 = rows 16-31 (copy1).
// Copy pairs read identical data -> all per-lane values identical across
// copies; readlane always pulls from copy0.
constexpr int lane_of_row(int m) { return (m & 15) + 32 * (m >> 4); }

// Sum over rows 0..31 of a per-lane value (wave-uniform result).
// 16-lane DPP butterfly sums each 16-lane row-group; lanes 0 / 32 then hold
// sum(rows 0-15) / sum(rows 16-31). VALU + readlane only — no DS pipe.
DEVINL float sum_rows(float x) {
  x += dpp_mov<0xB1>(x);   // quad_perm xor1
  x += dpp_mov<0x4E>(x);   // quad_perm xor2
  x += dpp_mov<0x141>(x);  // row_half_mirror
  x += dpp_mov<0x140>(x);  // row_mirror
  return readlane_f(x, 0) + readlane_f(x, 32);
}

// fp32 -> bf16 hi (round-half-up) + exact fp32 residual
DEVINL short bf_hi(float f, float& rem) {
  unsigned u = __float_as_uint(f);
  unsigned rh = (u + 0x8000u) >> 16;
  rem = f - __uint_as_float(rh << 16);
  return (short)rh;
}
DEVINL short bf_of(float f) {
  return (short)((__float_as_uint(f) + 0x8000u) >> 16);
}
DEVINL void cvt_hilo(float4 fa, float4 fb, short8& h, short8& lo) {
  float rm;
  h[0] = bf_hi(fa.x, rm); lo[0] = bf_of(rm);
  h[1] = bf_hi(fa.y, rm); lo[1] = bf_of(rm);
  h[2] = bf_hi(fa.z, rm); lo[2] = bf_of(rm);
  h[3] = bf_hi(fa.w, rm); lo[3] = bf_of(rm);
  h[4] = bf_hi(fb.x, rm); lo[4] = bf_of(rm);
  h[5] = bf_hi(fb.y, rm); lo[5] = bf_of(rm);
  h[6] = bf_hi(fb.z, rm); lo[6] = bf_of(rm);
  h[7] = bf_hi(fb.w, rm); lo[7] = bf_of(rm);
}
DEVINL f32x4 mfma_bf16(short8 a, short8 b, f32x4 c) {
  return __builtin_amdgcn_mfma_f32_16x16x32_bf16(a, b, c, 0, 0, 0);
}

// ---------- Householder step at compile-time pivot K: ZERO LDS --------------
// lane owns row `row` in r[32] (cols in registers -> loops truncate at K+1).
// Broadcasts of x (col K) and p (= C*v) go through v_readlane -> wave-uniform
// scalars (SGPR operands); reductions via DPP butterfly. Frozen rows have
// bv = nw = 0 (v_me masked), frozen cols are never touched (loops start at
// K+1) -> no junk anywhere.
template<int K>
DEVINL void house_step(float (&r)[32], int row,
                       float (&sd)[32], float (&se)[32]) {
  float xm = (row > K) ? r[K] : 0.0f;               // masked column K

  float sx[32];                                     // uniform broadcast of x
  #pragma unroll
  for (int m = K + 1; m < 32; ++m) sx[m] = readlane_f(r[K], lane_of_row(m));

  float nn = sum_rows(xm * xm);                     // ||x||^2 (uniform)
  float x0 = sx[K + 1];                             // pivot element
  float alpha = -copysignf(sqrtf(nn), x0);          // new subdiagonal e_K
  float denom = nn - alpha * x0;                    // >= 0
  float beta  = (denom > 1e-20f) ? rcp_f(denom) : 0.0f;   // 2 / v'v
  float v_me  = xm - ((row == K + 1) ? alpha : 0.0f);     // 0 for frozen rows
  float vpiv  = x0 - alpha;                         // v at pivot (uniform)

  // p_row = sum_{m>K} C[row][m] * v[m]   (2 accumulator chains)
  float a0 = 0.f, a1 = 0.f;
  #pragma unroll
  for (int m = K + 1; m < 32; ++m) {
    float vm = (m == K + 1) ? vpiv : sx[m];
    if ((m - K) & 1) a1 = fmaf(r[m], vm, a1);
    else             a0 = fmaf(r[m], vm, a0);
  }
  float p_me = a0 + a1;

  float G = sum_rows(v_me * p_me);                  // v'p (uniform; frozen
                                                    //  rows contribute 0)
  float sp[32];                                     // uniform broadcast of p
  #pragma unroll
  for (int m = K + 1; m < 32; ++m) sp[m] = readlane_f(p_me, lane_of_row(m));

  float bv = beta * v_me;                           // 0 for frozen rows
  float bp = (row > K) ? beta * p_me : 0.0f;
  float tv = (beta * beta * G) * v_me;              // 0 for frozen rows
  float nbv = -bv;
  float nw  = tv - bp;                              // r[m] += nbv*p[m]+nw*v[m]

  #pragma unroll
  for (int m = K + 1; m < 32; ++m) {
    float vm = (m == K + 1) ? vpiv : sx[m];
    r[m] = fmaf(nbv, sp[m], fmaf(nw, vm, r[m]));
  }

  sd[K] = readlane_f(r[K], lane_of_row(K));         // diag (row K frozen now)
  se[K] = readfirst_f(fabsf(alpha));                // |e_K|
}

template<int K>
DEVINL void house_all(float (&r)[32], int row,
                      float (&sd)[32], float (&se)[32]) {
  house_step<K>(r, row, sd, se);
  if constexpr (K < 30) house_all<K + 1>(r, row, sd, se);
}

// ================= fused kernel: 1 molecule per wave ========================
__global__ __launch_bounds__(256) void Correlation_85134841741354_kernel(
    const float* __restrict__ A, float* __restrict__ out, int M) {
  const int lane = threadIdx.x & 63;
  const int wave = threadIdx.x >> 6;
  const int q    = lane >> 4;            // Gram: 8-feature sub-chunk
  const int t    = lane & 15;            // Gram: MFMA row index
  const int row  = (lane & 15) + 16 * (lane >> 5);  // house: mirrored row
  const int mol  = blockIdx.x * 4 + wave;
  if (mol >= M) return;                  // M % 4 == 0

  // ONE C-tile per wave, stride 36. 4*1160*4B = 18.6 KB/block. LDS is used
  // ONLY for the one-time Gram->house transpose.
  __shared__ float ldsT[4][32 * 36 + 8];
  float* tq = &ldsT[wave][0];

  // ---------------- Gram via MFMA (hi/lo bf16 split; R5-proven) --------------
  {
    const float* Am = A + (size_t)mol * (32 * 128);
    f32x4 acc00 = {0.f, 0.f, 0.f, 0.f}, acc01 = {0.f, 0.f, 0.f, 0.f};
    f32x4 acc10 = {0.f, 0.f, 0.f, 0.f}, acc11 = {0.f, 0.f, 0.f, 0.f};
    #pragma unroll
    for (int c = 0; c < 4; ++c) {        // K chunks of 32 features
      const float* pr0 = Am + t * 128        + 32 * c + 8 * q;  // rows 0..15
      const float* pr1 = Am + (t + 16) * 128 + 32 * c + 8 * q;  // rows 16..31
      float4 fa0 = *(const float4*)(pr0);
      float4 fb0 = *(const float4*)(pr0 + 4);
      float4 fa1 = *(const float4*)(pr1);
      float4 fb1 = *(const float4*)(pr1 + 4);
      short8 h0, l0, h1, l1;
      cvt_hilo(fa0, fb0, h0, l0);
      cvt_hilo(fa1, fb1, h1, l1);
      // C = (hi+lo)(hi+lo)^T ~= hi hi^T + hi lo^T + lo hi^T  (drop lo lo^T)
      acc00 = mfma_bf16(h0, h0, acc00); acc00 = mfma_bf16(h0, l0, acc00); acc00 = mfma_bf16(l0, h0, acc00);
      acc01 = mfma_bf16(h0, h1, acc01); acc01 = mfma_bf16(h0, l1, acc01); acc01 = mfma_bf16(l0, h1, acc01);
      acc10 = mfma_bf16(h1, h0, acc10); acc10 = mfma_bf16(h1, l0, acc10); acc10 = mfma_bf16(l1, h0, acc10);
      acc11 = mfma_bf16(h1, h1, acc11); acc11 = mfma_bf16(h1, l1, acc11); acc11 = mfma_bf16(l1, h1, acc11);
    }
    // C/D layout: col = lane&15, row = (lane>>4)*4 + reg  [HW-verified]
    #pragma unroll
    for (int reg = 0; reg < 4; ++reg) {
      tq[(4 * q + reg) * 36 + t]           = acc00[reg];
      tq[(4 * q + reg) * 36 + 16 + t]      = acc01[reg];
      tq[(16 + 4 * q + reg) * 36 + t]      = acc10[reg];
      tq[(16 + 4 * q + reg) * 36 + 16 + t] = acc11[reg];
    }
  }
  LDS_FENCE();

  // readback in mirrored house layout (copy pairs read identical addresses)
  float r[32];
  #pragma unroll
  for (int c = 0; c < 8; ++c) {
    float4 x = *(const float4*)(tq + row * 36 + 4 * c);
    r[4 * c + 0] = x.x; r[4 * c + 1] = x.y;
    r[4 * c + 2] = x.z; r[4 * c + 3] = x.w;
  }

  // ---------------- Householder tridiagonalization (LDS-free) ---------------
  float sd[32], se[32];
  house_all<0>(r, row, sd, se);
  sd[31] = readlane_f(r[31], lane_of_row(31));
  se[31] = 0.0f;

  // ---------------- Gershgorin bracket (uniform VALU math) ------------------
  float glo = sd[0] - se[0];
  float ghi = sd[0] + se[0];
  #pragma unroll
  for (int i = 1; i < 32; ++i) {
    float rad = se[i] + se[i - 1];       // se = |e|, se[31] = 0
    glo = fminf(glo, sd[i] - rad);
    ghi = fmaxf(ghi, sd[i] + rad);
  }
  float lo = fmaxf(glo - 1e-3f, 0.0f);   // C = A A' is PSD
  float hi = ghi + 1e-3f;

  float se2[32];
  #pragma unroll
  for (int i = 0; i < 32; ++i) se2[i] = se[i] * se[i];

  // ---------------- Sturm bisection: 64 sigma points / round ----------------
  #pragma unroll
  for (int rr = 0; rr < 3; ++rr) {
    float stp = (hi - lo) * (1.0f / 65.0f);
    float sig = fmaf(stp, (float)(lane + 1), lo);
    float qq = sd[0] - sig;
    int cnt = (qq < 0.0f) ? 1 : 0;
    #pragma unroll
    for (int i = 1; i < 32; ++i) {
      float qs = (fabsf(qq) < 1e-12f) ? ((qq < 0.0f) ? -1e-12f : 1e-12f) : qq;
      qq = (sd[i] - sig) - se2[i - 1] * rcp_f(qs);
      cnt += (qq < 0.0f) ? 1 : 0;
    }
    unsigned long long m64 = __ballot(cnt >= 1);
    int b = (m64 == 0ull) ? 64 : (__ffsll((unsigned long long)m64) - 1);
    float nhi = (b == 64) ? hi : fmaf(stp, (float)(b + 1), lo);
    lo = fmaf(stp, (float)b, lo);
    hi = nhi;
  }

  if (lane == 0) out[mol] = 0.5f * (lo + hi);
}

extern "C" void kernel_launch(void* const* d_in, const int* in_sizes, int n_in,
                              void* d_out, int out_size, void* d_ws, size_t ws_size,
                              hipStream_t stream) {
  const float* A = (const float*)d_in[0];
  float* out = (float*)d_out;
  int n_atoms = in_sizes[1];          // 262144
  int M = n_atoms / 32;               // 8192 molecules
  int blocks = (M + 3) / 4;           // 4 molecules per 256-thread block
  hipLaunchKernelGGL(Correlation_85134841741354_kernel,
                     dim3(blocks), dim3(256), 0, stream, A, out, M);
}

// Round 8
// 212.670 us; speedup vs baseline: 1.1400x; 1.1400x over previous
//
#include <hip/hip_runtime.h>
#include <hip/hip_bf16.h>

#define DEVINL __device__ __forceinline__

typedef __attribute__((ext_vector_type(8))) short short8;   // 8 bf16 (4 VGPRs)
typedef __attribute__((ext_vector_type(4))) float f32x4;    // MFMA acc

DEVINL float rcp_f(float x) { return __builtin_amdgcn_rcpf(x); }

// compiler-level memory barrier: forces LDS stores to be emitted and kills
// stale-value forwarding (R0-proven). No instruction generated; within-wave
// DS ordering is guaranteed by hardware (DS pipe is in-order per wave).
#define LDS_FENCE() __asm__ volatile("" ::: "memory")

// DPP cross-lane moves within 16-lane rows (VALU pipe, no DS latency).
template<int CTRL>
DEVINL float dpp_mov(float x) {
  return __int_as_float(__builtin_amdgcn_update_dpp(
      0, __float_as_int(x), CTRL, 0xF, 0xF, true));
}
// xor-butterfly reduce over a 16-lane group (R0-proven bit-exact).
DEVINL float group_sum(float x) {
  x += dpp_mov<0xB1>(x);   // quad_perm xor1
  x += dpp_mov<0x4E>(x);   // quad_perm xor2
  x += dpp_mov<0x141>(x);  // row_half_mirror
  x += dpp_mov<0x140>(x);  // row_mirror
  return x;
}
DEVINL float group_min(float x) {
  x = fminf(x, dpp_mov<0xB1>(x));
  x = fminf(x, dpp_mov<0x4E>(x));
  x = fminf(x, dpp_mov<0x141>(x));
  x = fminf(x, dpp_mov<0x140>(x));
  return x;
}
DEVINL float group_max(float x) {
  x = fmaxf(x, dpp_mov<0xB1>(x));
  x = fmaxf(x, dpp_mov<0x4E>(x));
  x = fmaxf(x, dpp_mov<0x141>(x));
  x = fmaxf(x, dpp_mov<0x140>(x));
  return x;
}

// fp32 -> bf16 hi (round-half-up) + exact fp32 residual
DEVINL short bf_hi(float f, float& rem) {
  unsigned u = __float_as_uint(f);
  unsigned rh = (u + 0x8000u) >> 16;
  rem = f - __uint_as_float(rh << 16);
  return (short)rh;
}
DEVINL short bf_of(float f) {
  return (short)((__float_as_uint(f) + 0x8000u) >> 16);
}
DEVINL void cvt_hilo(float4 fa, float4 fb, short8& h, short8& lo) {
  float rm;
  h[0] = bf_hi(fa.x, rm); lo[0] = bf_of(rm);
  h[1] = bf_hi(fa.y, rm); lo[1] = bf_of(rm);
  h[2] = bf_hi(fa.z, rm); lo[2] = bf_of(rm);
  h[3] = bf_hi(fa.w, rm); lo[3] = bf_of(rm);
  h[4] = bf_hi(fb.x, rm); lo[4] = bf_of(rm);
  h[5] = bf_hi(fb.y, rm); lo[5] = bf_of(rm);
  h[6] = bf_hi(fb.z, rm); lo[6] = bf_of(rm);
  h[7] = bf_hi(fb.w, rm); lo[7] = bf_of(rm);
}
DEVINL f32x4 mfma_bf16(short8 a, short8 b, f32x4 c) {
  return __builtin_amdgcn_mfma_f32_16x16x32_bf16(a, b, c, 0, 0, 0);
}

// ---------- Householder step at compile-time pivot K (R0-proven) ------------
// 16 lanes per molecule; lane l owns rows l (r0) and l+16 (r1). Raw x staged
// to LDS BEFORE the norm reduction (roundtrip overlaps alpha/beta chain);
// pivot element fixed up in-register at constexpr index. Update uses folded
// scalars s_p, s_v (masked for frozen rows). Junk values only ever reach
// frozen columns of active rows, which are never meaningfully read again.
template<int K>
DEVINL void house_step(float (&r0)[32], float (&r1)[32], int l, int lane,
                       float* vbuf, float* pbuf, float* dbuf, float* ebuf) {
  constexpr int C0 = (K + 1) / 4;             // first float4 chunk touching v
  constexpr int PE = (K + 1) & 3;             // pivot element within chunk C0

  float xm0, xm1;
  if constexpr (K < 15) xm0 = (l > K) ? r0[K] : 0.0f;
  else                  xm0 = 0.0f;           // rows 0..15 all frozen
  if constexpr (K < 16) xm1 = r1[K];          // rows 16..31 all active
  else                  xm1 = (l > K - 16) ? r1[K] : 0.0f;

  vbuf[l] = xm0; vbuf[l + 16] = xm1;          // stage RAW x immediately
  LDS_FENCE();

  float xsrc = (K + 1 < 16) ? xm0 : xm1;      // compile-time select
  float x0 = __shfl(xsrc, (lane & 48) + ((K + 1) & 15), 64);
  float nn = group_sum(xm0 * xm0 + xm1 * xm1);

  float4 vc[8];                               // x chunks (read overlaps chain)
  #pragma unroll
  for (int c = C0; c < 8; ++c) vc[c] = *(const float4*)(vbuf + 4 * c);

  float alpha = -copysignf(sqrtf(nn), x0);    // new subdiagonal e_K
  float denom = nn - alpha * x0;              // >= 0
  float beta = (denom > 1e-20f) ? rcp_f(denom) : 0.0f;  // 2 / v'v

  float v0, v1;
  if constexpr (K + 1 < 16) {
    v0 = xm0 - ((l == K + 1) ? alpha : 0.0f);
    v1 = xm1;
  } else {
    v0 = 0.0f;
    v1 = xm1 - ((l == K + 1 - 16) ? alpha : 0.0f);
  }
  // fix the pivot element of the broadcast copy: v = x - alpha*e_{K+1}
  if constexpr (PE == 0)      vc[C0].x -= alpha;
  else if constexpr (PE == 1) vc[C0].y -= alpha;
  else if constexpr (PE == 2) vc[C0].z -= alpha;
  else                        vc[C0].w -= alpha;

  float p0 = 0.0f;
  if constexpr (K < 15) {
    float a0 = 0.0f, a1 = 0.0f;
    #pragma unroll
    for (int c = C0; c < 8; ++c) {
      a0 = fmaf(r0[4 * c + 0], vc[c].x, a0); a1 = fmaf(r0[4 * c + 1], vc[c].y, a1);
      a0 = fmaf(r0[4 * c + 2], vc[c].z, a0); a1 = fmaf(r0[4 * c + 3], vc[c].w, a1);
    }
    p0 = a0 + a1;
  }
  float b0 = 0.0f, b1 = 0.0f;
  #pragma unroll
  for (int c = C0; c < 8; ++c) {
    b0 = fmaf(r1[4 * c + 0], vc[c].x, b0); b1 = fmaf(r1[4 * c + 1], vc[c].y, b1);
    b0 = fmaf(r1[4 * c + 2], vc[c].z, b0); b1 = fmaf(r1[4 * c + 3], vc[c].w, b1);
  }
  float p1 = b0 + b1;

  pbuf[l] = p0; pbuf[l + 16] = p1;            // store raw p = C*v
  LDS_FENCE();
  float G = group_sum(v0 * p0 + v1 * p1);     // overlaps p readback
  float c2 = 0.5f * beta * beta * G;

  // folded update scalars: r -= s_p*p[m] + s_v*v[m]   (== v*w[m] + w*v[m])
  float s_p0 = 0.0f, s_v0 = 0.0f;
  if constexpr (K < 15) {
    bool act0 = (l > K);
    s_p0 = beta * v0;                                       // 0 if frozen
    s_v0 = act0 ? fmaf(-2.0f * c2, v0, beta * p0) : 0.0f;
  }
  float s_p1 = beta * v1;                                   // v1 masked already
  float s_v1;
  if constexpr (K < 16) s_v1 = fmaf(-2.0f * c2, v1, beta * p1);
  else                  s_v1 = (l > K - 16) ? fmaf(-2.0f * c2, v1, beta * p1) : 0.0f;

  #pragma unroll
  for (int c = C0; c < 8; ++c) {
    float4 pc = *(const float4*)(pbuf + 4 * c);
    if constexpr (K < 15) {
      r0[4 * c + 0] -= s_p0 * pc.x + s_v0 * vc[c].x;
      r0[4 * c + 1] -= s_p0 * pc.y + s_v0 * vc[c].y;
      r0[4 * c + 2] -= s_p0 * pc.z + s_v0 * vc[c].z;
      r0[4 * c + 3] -= s_p0 * pc.w + s_v0 * vc[c].w;
    }
    r1[4 * c + 0] -= s_p1 * pc.x + s_v1 * vc[c].x;
    r1[4 * c + 1] -= s_p1 * pc.y + s_v1 * vc[c].y;
    r1[4 * c + 2] -= s_p1 * pc.z + s_v1 * vc[c].z;
    r1[4 * c + 3] -= s_p1 * pc.w + s_v1 * vc[c].w;
  }

  if constexpr (K < 16) {
    if (l == K) { dbuf[K] = r0[K]; ebuf[K] = alpha; }
  } else {
    if (l == K - 16) { dbuf[K] = r1[K]; ebuf[K] = alpha; }
  }
}

template<int K>
DEVINL void house_all(float (&r0)[32], float (&r1)[32], int l, int lane,
                      float* vbuf, float* pbuf, float* dbuf, float* ebuf) {
  house_step<K>(r0, r1, l, lane, vbuf, pbuf, dbuf, ebuf);
  if constexpr (K < 30) house_all<K + 1>(r0, r1, l, lane, vbuf, pbuf, dbuf, ebuf);
}

__global__ __launch_bounds__(256) void Correlation_85134841741354_kernel(
    const float* __restrict__ A, float* __restrict__ out, int M) {
  const int lane = threadIdx.x & 63;
  const int wave = threadIdx.x >> 6;
  const int q    = lane >> 4;            // quad == eigensolve group
  const int t    = lane & 15;            // lane within group / MFMA row index
  const int molbase = blockIdx.x * 16 + wave * 4;
  if (molbase >= M) return;              // M % 16 == 0

  // TWO C-tiles per wave (R0 had four): Gram runs in two passes of 2 mols,
  // with readback between. 4*2*1160*4B = 37.1 KB/block -> 4 blocks/CU
  // (R0: 74 KB -> 2 blocks/CU). Same VALU-efficient 16-lane house layout.
  __shared__ float ldsT[4][2][32 * 36 + 8];

  float r0[32], r1[32];

  // ---------------- Gram via MFMA, two passes of 2 molecules -----------------
  #pragma unroll 1
  for (int p = 0; p < 2; ++p) {
    #pragma unroll 1
    for (int g = 0; g < 2; ++g) {
      const float* Am = A + (size_t)(molbase + 2 * p + g) * (32 * 128);
      f32x4 acc00 = {0.f, 0.f, 0.f, 0.f}, acc01 = {0.f, 0.f, 0.f, 0.f};
      f32x4 acc10 = {0.f, 0.f, 0.f, 0.f}, acc11 = {0.f, 0.f, 0.f, 0.f};
      #pragma unroll
      for (int c = 0; c < 4; ++c) {      // K chunks of 32 features
        const float* pr0 = Am + t * 128        + 32 * c + 8 * q;  // rows 0..15
        const float* pr1 = Am + (t + 16) * 128 + 32 * c + 8 * q;  // rows 16..31
        float4 fa0 = *(const float4*)(pr0);
        float4 fb0 = *(const float4*)(pr0 + 4);
        float4 fa1 = *(const float4*)(pr1);
        float4 fb1 = *(const float4*)(pr1 + 4);
        short8 h0, l0, h1, l1;
        cvt_hilo(fa0, fb0, h0, l0);
        cvt_hilo(fa1, fb1, h1, l1);
        // C = (hi+lo)(hi+lo)^T ~= hi hi^T + hi lo^T + lo hi^T  (drop lo lo^T)
        acc00 = mfma_bf16(h0, h0, acc00); acc00 = mfma_bf16(h0, l0, acc00); acc00 = mfma_bf16(l0, h0, acc00);
        acc01 = mfma_bf16(h0, h1, acc01); acc01 = mfma_bf16(h0, l1, acc01); acc01 = mfma_bf16(l0, h1, acc01);
        acc10 = mfma_bf16(h1, h0, acc10); acc10 = mfma_bf16(h1, l0, acc10); acc10 = mfma_bf16(l1, h0, acc10);
        acc11 = mfma_bf16(h1, h1, acc11); acc11 = mfma_bf16(h1, l1, acc11); acc11 = mfma_bf16(l1, h1, acc11);
      }
      // C/D layout: col = lane&15, row = (lane>>4)*4 + reg  [HW-verified]
      float* tg = &ldsT[wave][g][0];
      #pragma unroll
      for (int reg = 0; reg < 4; ++reg) {
        tg[(4 * q + reg) * 36 + t]           = acc00[reg];
        tg[(4 * q + reg) * 36 + 16 + t]      = acc01[reg];
        tg[(16 + 4 * q + reg) * 36 + t]      = acc10[reg];
        tg[(16 + 4 * q + reg) * 36 + 16 + t] = acc11[reg];
      }
    }
    LDS_FENCE();
    // groups 2p, 2p+1 read their molecule (tile q&1) NOW, before pass p+1
    // overwrites the tiles. In-order DS per wave orders reads before the
    // next pass's writes (same aliasing discipline R0 proved).
    if ((q >> 1) == p) {
      const float* tq = &ldsT[wave][q & 1][0];
      #pragma unroll
      for (int c = 0; c < 8; ++c) {
        float4 x = *(const float4*)(tq + t * 36 + 4 * c);
        r0[4 * c + 0] = x.x; r0[4 * c + 1] = x.y;
        r0[4 * c + 2] = x.z; r0[4 * c + 3] = x.w;
        float4 y = *(const float4*)(tq + (t + 16) * 36 + 4 * c);
        r1[4 * c + 0] = y.x; r1[4 * c + 1] = y.y;
        r1[4 * c + 2] = y.z; r1[4 * c + 3] = y.w;
      }
    }
    LDS_FENCE();
  }

  // Householder scratch carved from the (now dead) tiles; groups staggered by
  // 296 floats = 8 banks -> worst 2-way on 64-lane ds_write (free).
  // 4 groups * 296 = 1184 floats <= 2*1160 available. 296 % 4 == 0 (float4 ok).
  float* scr  = &ldsT[wave][0][0] + q * 296;
  float* vbuf = scr;
  float* pbuf = scr + 40;
  float* dbuf = scr + 80;
  float* ebuf = scr + 120;

  // ---------------- Householder tridiagonalization ---------------------------
  house_all<0>(r0, r1, t, lane, vbuf, pbuf, dbuf, ebuf);
  if (t == 15) { dbuf[31] = r1[31]; ebuf[31] = 0.0f; }
  LDS_FENCE();

  // ---------------- Gershgorin bracket ---------------------------------------
  float d0 = dbuf[t], d1 = dbuf[t + 16];
  float eh0 = ebuf[t];
  float el0 = (t > 0) ? ebuf[t - 1] : 0.0f;
  float eh1 = ebuf[t + 16];                  // ebuf[31] = 0
  float el1 = ebuf[t + 15];                  // t=0 -> edge (15,16)
  float rad0 = fabsf(eh0) + fabsf(el0);
  float rad1 = fabsf(eh1) + fabsf(el1);
  float glo = group_min(fminf(d0 - rad0, d1 - rad1));
  float ghi = group_max(fmaxf(d0 + rad0, d1 + rad1));
  float lo = fmaxf(glo - 1e-3f, 0.0f);       // C = A A' is PSD
  float hi = ghi + 1e-3f;

  // tridiagonal into registers (uniform per group)
  float vd[32], ve2[32];
  #pragma unroll
  for (int c = 0; c < 8; ++c) {
    float4 dc = *(const float4*)(dbuf + 4 * c);
    float4 ec = *(const float4*)(ebuf + 4 * c);
    vd[4 * c + 0] = dc.x; vd[4 * c + 1] = dc.y;
    vd[4 * c + 2] = dc.z; vd[4 * c + 3] = dc.w;
    ve2[4 * c + 0] = ec.x * ec.x; ve2[4 * c + 1] = ec.y * ec.y;
    ve2[4 * c + 2] = ec.z * ec.z; ve2[4 * c + 3] = ec.w * ec.w;
  }

  // ---------------- Sturm bisection: 16 sigma points / round -----------------
  #pragma unroll
  for (int rr = 0; rr < 3; ++rr) {
    float stp = (hi - lo) * (1.0f / 17.0f);
    float sig = fmaf(stp, (float)(t + 1), lo);
    float qq = vd[0] - sig;
    int cnt = (qq < 0.0f) ? 1 : 0;
    #pragma unroll
    for (int i = 1; i < 32; ++i) {
      float qs = (fabsf(qq) < 1e-12f) ? ((qq < 0.0f) ? -1e-12f : 1e-12f) : qq;
      qq = (vd[i] - sig) - ve2[i - 1] * rcp_f(qs);
      cnt += (qq < 0.0f) ? 1 : 0;
    }
    unsigned long long m64 = __ballot(cnt >= 1);
    unsigned hm = (unsigned)((m64 >> (q * 16)) & 0xFFFFu);
    int b = (hm == 0u) ? 16 : (__ffs(hm) - 1);
    float nhi = (b == 16) ? hi : fmaf(stp, (float)(b + 1), lo);
    lo = fmaf(stp, (float)b, lo);
    hi = nhi;
  }

  if (t == 0) out[molbase + q] = 0.5f * (lo + hi);
}

extern "C" void kernel_launch(void* const* d_in, const int* in_sizes, int n_in,
                              void* d_out, int out_size, void* d_ws, size_t ws_size,
                              hipStream_t stream) {
  const float* A = (const float*)d_in[0];
  float* out = (float*)d_out;
  int n_atoms = in_sizes[1];          // 262144
  int M = n_atoms / 32;               // 8192 molecules
  int blocks = (M + 15) / 16;         // 16 molecules per 256-thread block
  hipLaunchKernelGGL(Correlation_85134841741354_kernel,
                     dim3(blocks), dim3(256), 0, stream, A, out, M);
}